// Round 4
// baseline (145.795 us; speedup 1.0000x reference)
//
#include <hip/hip_runtime.h>

#define NEV 256   // events
#define NP  512   // particles per event
#define HD  16    // hidden dim
#define KBS 36    // kb row stride words: 32 keys + 4 pad; edge phase: gg[0..16) bb[16..32)

typedef short s16x8  __attribute__((ext_vector_type(8)));
typedef float f32x16 __attribute__((ext_vector_type(16)));

#define Z16 {0.f,0.f,0.f,0.f,0.f,0.f,0.f,0.f,0.f,0.f,0.f,0.f,0.f,0.f,0.f,0.f}

__device__ __forceinline__ float elu_f(float x) {
    return x > 0.0f ? x : (__expf(x) - 1.0f);
}
__device__ __forceinline__ unsigned umin_(unsigned a, unsigned b) { return a < b ? a : b; }
__device__ __forceinline__ unsigned med3u(unsigned a, unsigned b, unsigned c) {
    unsigned d;
    asm("v_med3_u32 %0, %1, %2, %3" : "=v"(d) : "v"(a), "v"(b), "v"(c));
    return d;
}
__device__ __forceinline__ unsigned short rneb(float f) {   // f32 -> bf16 bits RNE
    unsigned u = __float_as_uint(f);
    return (unsigned short)((u + 0x7FFFu + ((u >> 16) & 1u)) >> 16);
}
__device__ __forceinline__ float bits2f(unsigned short b) {
    return __uint_as_float(((unsigned)b) << 16);
}
__device__ __forceinline__ unsigned sx32(unsigned v) {      // partner lane (l^32)
    return (unsigned)__shfl_xor((int)v, 32, 64);
}

__global__ __launch_bounds__(1024, 4) void suep_fused(
    const float* __restrict__ x_pf,
    const float* __restrict__ W1,  const float* __restrict__ b1,
    const float* __restrict__ W2,  const float* __restrict__ b2,
    const float* __restrict__ Wc,  const float* __restrict__ bc,
    const float* __restrict__ Wo1, const float* __restrict__ bo1,
    const float* __restrict__ Wo2, const float* __restrict__ bo2,
    const float* __restrict__ Wo3, const float* __restrict__ bo3,
    float* __restrict__ out)
{
    __shared__ unsigned kb[NP * KBS];   // 72 KB: strip keys; aliased gg/bb + f rows
    __shared__ s16x8 fragH[16][64];     // 16 KB bf16 hi fragments
    __shared__ s16x8 fragL[16][64];     // 16 KB bf16 lo fragments
    __shared__ float sSq[NP];
    __shared__ float sW1[64], sB1[HD], sW2[256], sB2[HD];
    __shared__ float sWcB[256], sWcD[256], sBc[HD];
    __shared__ float sWo1[128], sBo1[8], sWo2[32], sBo2[4], sWo3[4], sBo3[1];
    __shared__ float sRedM[8];
    __shared__ float sRed[16][HD];
    __shared__ float sPool[HD];

    const int tid = threadIdx.x, ev = blockIdx.x;
    const int l = tid & 63, w = tid >> 6;      // 16 waves, wave w owns rows [32w,32w+32)
    const int n = tid & 511;                   // node role (halves duplicate)
    const bool loT = (tid < 512);
    const int c32 = l & 31, kh = l >> 5;
    const int row = 32 * w + c32;              // this lane's scan/gather row

    // ---- stage weights ----
    if (tid < 64) sW1[tid] = W1[tid];
    if (tid < HD) { sB1[tid] = b1[tid]; sB2[tid] = b2[tid]; sBc[tid] = bc[tid]; }
    if (tid < 256) {
        sW2[tid] = W2[tid];
        float wb = Wc[256 + tid];
        sWcB[tid] = wb;
        sWcD[tid] = Wc[tid] - wb;
    }
    if (tid < 128) sWo1[tid] = Wo1[tid];
    if (tid < 8)   sBo1[tid] = bo1[tid];
    if (tid < 32)  sWo2[tid] = Wo2[tid];
    if (tid < 4)   { sBo2[tid] = bo2[tid]; sWo3[tid] = Wo3[tid]; }
    if (tid == 0)  sBo3[0] = bo3[0];
    __syncthreads();

    // ---- encoder, duplicated across thread halves (both need h[n]) ----
    float hr[HD];
    {
        float4 xv = ((const float4*)x_pf)[ev * NP + n];
        float e1[HD];
#pragma unroll
        for (int c = 0; c < HD; ++c) {
            float a = sB1[c];
            a = fmaf(xv.x, sW1[0 * HD + c], a);
            a = fmaf(xv.y, sW1[1 * HD + c], a);
            a = fmaf(xv.z, sW1[2 * HD + c], a);
            a = fmaf(xv.w, sW1[3 * HD + c], a);
            e1[c] = elu_f(a);
        }
#pragma unroll
        for (int c = 0; c < HD; ++c) {
            float a = sB2[c];
#pragma unroll
            for (int f = 0; f < HD; ++f) a = fmaf(e1[f], sW2[f * HD + c], a);
            hr[c] = elu_f(a);
        }
    }

    // ---- build bf16 hi/lo frags (role-split), |h~|^2, C offset; one barrier ----
    auto build_frags = [&]() -> float {
        s16x8 v0, v1;
        float sq = 0.0f;
#pragma unroll
        for (int k = 0; k < HD; ++k) {
            unsigned short hb = rneb(hr[k]);
            float fh = bits2f(hb);
            unsigned short lb = rneb(hr[k] - fh);
            if (loT) {
                float ht = fh + bits2f(lb);
                sq = fmaf(ht, ht, sq);
            }
            unsigned short vb = loT ? hb : lb;
            if (k < 8) v0[k] = (short)vb; else v1[k - 8] = (short)vb;
        }
        s16x8 (*fr)[64] = loT ? fragH : fragL;
        fr[n >> 5][n & 31]      = v0;
        fr[n >> 5][(n & 31) + 32] = v1;
        if (loT) {
            sSq[n] = sq;
            float m = sq;
#pragma unroll
            for (int d = 32; d >= 1; d >>= 1) m = fmaxf(m, __shfl_xor(m, d, 64));
            if (l == 0) sRedM[w] = m;
        }
        __syncthreads();               // BAR-A: frags + sSq + sRedM published
        float mx = sRedM[0];
#pragma unroll
        for (int i = 1; i < 8; ++i) mx = fmaxf(mx, sRedM[i]);
        return mx + 1.0f;
    };

    // One DynamicEdgeConv. Updates hr in place unless last; last -> pooled result.
    auto do_conv = [&](bool last) {
        float Cv = build_frags();

        // this wave's A fragments (rows 32w..32w+32), strip-invariant
        s16x8 Ah = fragH[w][l], Al = fragL[w][l];

        unsigned t0 = ~0u, t1 = ~0u, t2 = ~0u, t3 = ~0u,
                 t4 = ~0u, t5 = ~0u, t6 = ~0u, t7 = ~0u;
#define INS(KEY) do { unsigned kk = (KEY);              \
        t7 = med3u(t6, kk, t7); t6 = med3u(t5, kk, t6); \
        t5 = med3u(t4, kk, t5); t4 = med3u(t3, kk, t4); \
        t3 = med3u(t2, kk, t3); t2 = med3u(t1, kk, t2); \
        t1 = med3u(t0, kk, t1); t0 = umin_(kk, t0); } while (0)

        // G-tile (rows [32w,32w+32), cols [32s,32s+32)):
        // G = Hh.Hh^T + Hh.Hl^T + Hl.Hh^T  (rel err ~2^-17)
        auto cs = [&](int s, f32x16& a) {
            s16x8 Bh = fragH[s][l], Bl = fragL[s][l];
            f32x16 z = Z16;
            a = __builtin_amdgcn_mfma_f32_32x32x16_bf16(Al, Bh, z, 0, 0, 0);
            a = __builtin_amdgcn_mfma_f32_32x32x16_bf16(Ah, Bl, a, 0, 0, 0);
            a = __builtin_amdgcn_mfma_f32_32x32x16_bf16(Ah, Bh, a, 0, 0, 0);
        };

        // keys: bits(C + sq_col - 2G) & ~511 | col  (row-const sq_i dropped; >0 by C)
        // C/D layout: col = lane&31, row = (q&3)+8*(q>>2)+4*(lane>>5)
        unsigned* wp = &kb[(32 * w + 4 * kh) * KBS + c32];
        auto st = [&](int s, const f32x16& a) {
            float base = Cv + sSq[32 * s + c32];
            unsigned colb = (unsigned)(32 * s + c32);
#pragma unroll
            for (int q = 0; q < 16; ++q) {
                const int roff = (q & 3) + 8 * (q >> 2);
                wp[roff * KBS] =
                    (__float_as_uint(fmaf(-2.0f, a[q], base)) & 0xFFFFFE00u) | colb;
            }
        };

        // lane scans row 32w+(l&31), col-half kh: exactly this wave's tile
        const uint4* rp = (const uint4*)&kb[row * KBS + 16 * kh];
        auto scan = [&]() {
#pragma unroll
            for (int g = 0; g < 4; ++g) {
                uint4 k4 = rp[g];
                INS(k4.x); INS(k4.y); INS(k4.z); INS(k4.w);
            }
        };

        // barrier-free strip loop (producer wave == consumer wave)
        f32x16 a0, a1;
        cs(0, a0);
        for (int s = 0; s < 16; s += 2) {
            st(s, a0);
            cs(s + 1, a1);                       // compiler's MFMA wait drains st
            asm volatile("s_waitcnt lgkmcnt(0)" ::: "memory");   // ~free; pins scan
            scan();
            st(s + 1, a1);
            if (s + 2 < 16) cs(s + 2, a0);
            asm volatile("s_waitcnt lgkmcnt(0)" ::: "memory");
            scan();
        }
#undef INS

        // merge col-halves: exact top-8 of two sorted-8 = half-cleaner (set-wise)
        unsigned m0 = umin_(t0, sx32(t7)), m1 = umin_(t1, sx32(t6)),
                 m2 = umin_(t2, sx32(t5)), m3 = umin_(t3, sx32(t4)),
                 m4 = umin_(t4, sx32(t3)), m5 = umin_(t5, sx32(t2)),
                 m6 = umin_(t6, sx32(t1)), m7 = umin_(t7, sx32(t0));

        // ---- edge MLP, role-split: loT -> gg = h@WcB ; hiT -> bb = bc + h@WcD ----
        float gb[HD];
        {
            const float* Wm = loT ? sWcB : sWcD;
#pragma unroll
            for (int c = 0; c < HD; ++c) gb[c] = loT ? 0.0f : sBc[c];
#pragma unroll
            for (int f = 0; f < HD; ++f) {
                float hf = hr[f];
#pragma unroll
                for (int c = 0; c < HD; ++c) gb[c] = fmaf(hf, Wm[f * HD + c], gb[c]);
            }
        }
        __syncthreads();               // BAR-B: all scans done; kb reuse as gg/bb
        float* gr = (float*)&kb[n * KBS + (loT ? 0 : 16)];
        ((float4*)gr)[0] = make_float4(gb[0], gb[1], gb[2], gb[3]);
        ((float4*)gr)[1] = make_float4(gb[4], gb[5], gb[6], gb[7]);
        ((float4*)gr)[2] = make_float4(gb[8], gb[9], gb[10], gb[11]);
        ((float4*)gr)[3] = make_float4(gb[12], gb[13], gb[14], gb[15]);
        __syncthreads();               // BAR-C: gg/bb published

        // gather 4 neighbors per lane (kh=0 -> m0..3, kh=1 -> m4..7), max over gg
        int j0 = (int)((kh ? m4 : m0) & 511u), j1 = (int)((kh ? m5 : m1) & 511u);
        int j2 = (int)((kh ? m6 : m2) & 511u), j3 = (int)((kh ? m7 : m3) & 511u);
        float z[HD];
        {
            const float4* g0 = (const float4*)&kb[j0 * KBS];
            const float4* g1 = (const float4*)&kb[j1 * KBS];
            const float4* g2 = (const float4*)&kb[j2 * KBS];
            const float4* g3 = (const float4*)&kb[j3 * KBS];
#pragma unroll
            for (int qq = 0; qq < 4; ++qq) {
                float4 va = g0[qq], vb = g1[qq], vc = g2[qq], vd = g3[qq];
                z[4*qq+0] = fmaxf(fmaxf(va.x, vb.x), fmaxf(vc.x, vd.x));
                z[4*qq+1] = fmaxf(fmaxf(va.y, vb.y), fmaxf(vc.y, vd.y));
                z[4*qq+2] = fmaxf(fmaxf(va.z, vb.z), fmaxf(vc.z, vd.z));
                z[4*qq+3] = fmaxf(fmaxf(va.w, vb.w), fmaxf(vc.w, vd.w));
            }
        }
#pragma unroll
        for (int c = 0; c < HD; ++c) z[c] = fmaxf(z[c], __shfl_xor(z[c], 32, 64));

        float fo[HD];
        if (kh == 0) {                 // lane<32 finalizes row 'row'
            const float4* br = (const float4*)&kb[row * KBS + 16];
#pragma unroll
            for (int qq = 0; qq < 4; ++qq) {
                float4 vb = br[qq];
                fo[4*qq+0] = elu_f(z[4*qq+0] + vb.x);
                fo[4*qq+1] = elu_f(z[4*qq+1] + vb.y);
                fo[4*qq+2] = elu_f(z[4*qq+2] + vb.z);
                fo[4*qq+3] = elu_f(z[4*qq+3] + vb.w);
            }
        }

        if (!last) {
            __syncthreads();           // BAR-D: gathers done; kb rows reusable
            if (kh == 0) {
                float4* fr = (float4*)&kb[row * KBS];
                fr[0] = make_float4(fo[0], fo[1], fo[2], fo[3]);
                fr[1] = make_float4(fo[4], fo[5], fo[6], fo[7]);
                fr[2] = make_float4(fo[8], fo[9], fo[10], fo[11]);
                fr[3] = make_float4(fo[12], fo[13], fo[14], fo[15]);
            }
            __syncthreads();           // BAR-E: f published
            const float4* hrp = (const float4*)&kb[n * KBS];
#pragma unroll
            for (int qq = 0; qq < 4; ++qq) {
                float4 v = hrp[qq];
                hr[4*qq+0] = v.x; hr[4*qq+1] = v.y; hr[4*qq+2] = v.z; hr[4*qq+3] = v.w;
            }
        } else {
            // ---- mean pool directly from lane-row space (kh==0 lanes hold f2) ----
#pragma unroll
            for (int m = 16; m >= 1; m >>= 1) {
#pragma unroll
                for (int c = 0; c < HD; ++c) fo[c] += __shfl_xor(fo[c], m, 64);
            }
            if (l == 0) {
                ((float4*)(&sRed[w][0]))[0] = make_float4(fo[0], fo[1], fo[2], fo[3]);
                ((float4*)(&sRed[w][0]))[1] = make_float4(fo[4], fo[5], fo[6], fo[7]);
                ((float4*)(&sRed[w][0]))[2] = make_float4(fo[8], fo[9], fo[10], fo[11]);
                ((float4*)(&sRed[w][0]))[3] = make_float4(fo[12], fo[13], fo[14], fo[15]);
            }
            __syncthreads();
            if (tid < HD) {
                float s = 0.0f;
#pragma unroll
                for (int ww = 0; ww < 16; ++ww) s += sRed[ww][tid];
                sPool[tid] = s * (1.0f / (float)NP);
            }
            __syncthreads();
        }
    };

    do_conv(false);
    do_conv(true);

    // ---- head MLP + outputs ----
    if (tid == 0) {
        float o1[8];
#pragma unroll
        for (int c = 0; c < 8; ++c) {
            float a = sBo1[c];
#pragma unroll
            for (int f = 0; f < HD; ++f) a = fmaf(sPool[f], sWo1[f * 8 + c], a);
            o1[c] = elu_f(a);
        }
        float o2[4];
#pragma unroll
        for (int c = 0; c < 4; ++c) {
            float a = sBo2[c];
#pragma unroll
            for (int f = 0; f < 8; ++f) a = fmaf(o1[f], sWo2[f * 4 + c], a);
            o2[c] = elu_f(a);
        }
        float o3 = sBo3[0];
#pragma unroll
        for (int f = 0; f < 4; ++f) o3 = fmaf(o2[f], sWo3[f], o3);
        out[ev] = o3;
        out[NEV + ev] = (float)ev;
    }
}

extern "C" void kernel_launch(void* const* d_in, const int* in_sizes, int n_in,
                              void* d_out, int out_size, void* d_ws, size_t ws_size,
                              hipStream_t stream) {
    const float* x_pf = (const float*)d_in[0];
    // d_in[1] = batch_pf (contiguous equal-size events; unused)
    const float* W1  = (const float*)d_in[2];
    const float* b1  = (const float*)d_in[3];
    const float* W2  = (const float*)d_in[4];
    const float* b2  = (const float*)d_in[5];
    const float* Wc  = (const float*)d_in[6];
    const float* bc  = (const float*)d_in[7];
    const float* Wo1 = (const float*)d_in[8];
    const float* bo1 = (const float*)d_in[9];
    const float* Wo2 = (const float*)d_in[10];
    const float* bo2 = (const float*)d_in[11];
    const float* Wo3 = (const float*)d_in[12];
    const float* bo3 = (const float*)d_in[13];
    float* out = (float*)d_out;

    hipLaunchKernelGGL(suep_fused, dim3(NEV), dim3(1024), 0, stream,
                       x_pf, W1, b1, W2, b2, Wc, bc,
                       Wo1, bo1, Wo2, bo2, Wo3, bo3, out);
}